// Round 8
// baseline (223.052 us; speedup 1.0000x reference)
//
#include <hip/hip_runtime.h>
#include <hip/hip_bf16.h>
#include <math.h>

#define D_L   256
#define L_L   64
#define K_C   8
#define BATCH 2048
#define NTOT  16384
#define ENC_COLS 1536
#define LOG2PI 1.8378770664093453f
#define L2E    1.4426950408889634f
#define LN2    0.6931471805599453f
#define C_HL2E 0.7213475204444817f   // 0.5 * log2(e)

typedef __attribute__((ext_vector_type(8)))  short short8;
typedef __attribute__((ext_vector_type(8)))  unsigned short ushort8;
typedef __attribute__((ext_vector_type(4)))  unsigned short ushort4_;
typedef __attribute__((ext_vector_type(4)))  float float4_;
typedef __attribute__((ext_vector_type(16))) float float16_;

#if defined(__has_builtin)
#  if __has_builtin(__builtin_amdgcn_exp2f)
#    define EXP2F(x) __builtin_amdgcn_exp2f(x)
#  endif
#  if __has_builtin(__builtin_amdgcn_logf)
#    define LOG2F(x) __builtin_amdgcn_logf(x)
#  endif
#endif
#ifndef EXP2F
#  define EXP2F(x) __expf((x) * LN2)
#endif
#ifndef LOG2F
#  define LOG2F(x) (__logf(x) * L2E)
#endif

// workspace layout (float offsets), total ~16.25 MB
#define OFF_PE    0                                 // 2048*1536 f32
#define OFF_H     (BATCH * ENC_COLS)                // 16384*64 bf16, 32x32 A-frag order
#define OFF_WET2  (OFF_H + NTOT * L_L / 2)          // 1536*256 bf16, 32x32 B-frag order
#define OFF_WDT2  (OFF_WET2 + ENC_COLS * D_L / 2)   // 6144*64 bf16, 32x32 B-frag order
#define OFF_ACC   (OFF_WDT2 + 6144 * 64 / 2)        // 1 f32 accumulator
#define OFF_CNT   (OFF_ACC + 1)                     // 1 u32 block counter

__device__ __forceinline__ unsigned short f2bf(float f) {
  unsigned u = __float_as_uint(f);
  return (unsigned short)((u + 0x7fffu + ((u >> 16) & 1u)) >> 16);
}

// ---------------------------------------------------------------------------
// prep: 192 uniform 64x64 tile blocks converting W's into MFMA-B-fragment
// order bf16, + 1 block zeroing accumulator+counter. Fragment order per 64x64
// (k x col) tile: [dg 2][st 4][q 2][col 32][j 8],
//   element = W[k = st*16+q*8+j][dg*32+col]
// ---------------------------------------------------------------------------
__global__ __launch_bounds__(256) void k_prep(
    const float* __restrict__ We, const float* __restrict__ Wd,
    unsigned short* __restrict__ WeT2, unsigned short* __restrict__ WdT2,
    float* __restrict__ accf, unsigned* __restrict__ counter)
{
  const int bid = blockIdx.x, t = threadIdx.x;
  if (bid == 192) {
    if (t == 0) { accf[0] = 0.0f; counter[0] = 0u; }
    return;
  }

  const float* src; int C, rowbase, colbase; float scale;
  unsigned short* dst;
  if (bid < 96) {
    const int comp = bid / 12, p = (bid % 12) >> 2, dt = bid & 3;
    src = Wd; C = 6144; rowbase = 0;
    colbase = p * 2048 + comp * 256 + dt * 64;
    scale = p ? L2E : 1.0f;
    dst = WdT2 + (size_t)bid * 4096;            // tile idx == (comp*3+p)*4+dt == bid
  } else {
    const int idx = bid - 96;
    src = We; C = ENC_COLS; rowbase = (idx & 3) * 64;
    colbase = (idx >> 2) * 64;
    scale = 1.0f;
    dst = WeT2 + (size_t)idx * 4096;            // tile idx == cblk*4+kc
  }

  __shared__ float tile[64][65];
  {
    const int col = t & 63, w0 = t >> 6;
    #pragma unroll
    for (int i = 0; i < 16; ++i) {
      const int r = w0 + i * 4;
      tile[r][col] = src[(size_t)(rowbase + r) * C + colbase + col] * scale;
    }
  }
  __syncthreads();
  const int st = t >> 6, q = (t >> 5) & 1, c = t & 31;
  #pragma unroll
  for (int dg = 0; dg < 2; ++dg) {
    ushort8 o;
    #pragma unroll
    for (int j = 0; j < 8; ++j) o[j] = f2bf(tile[st * 16 + q * 8 + j][dg * 32 + c]);
    *(ushort8*)(dst + ((((size_t)dg * 4 + st) * 2 + q) * 32 + c) * 8) = o;
  }
}

// ---------------------------------------------------------------------------
// Encoder GEMM: pe = x @ We + be. 64x64 tile, full K=256 staged in LDS once
// (single barrier), B-fragments streamed from L2. grid (24, 32) x 256.
// ---------------------------------------------------------------------------
__global__ __launch_bounds__(256) void k_enc(
    const float* __restrict__ x, const unsigned short* __restrict__ WeT2,
    const float* __restrict__ be, float* __restrict__ pe)
{
  __shared__ __align__(16) unsigned short as_[64 * 264];
  const int t = threadIdx.x;
  const int w = t >> 6, l = t & 63;
  const int col = l & 31, q = l >> 5;
  const int rg = w >> 1, dg = w & 1;
  const int m0 = blockIdx.y * 64, cblk = blockIdx.x, c0 = cblk * 64;

  {
    const int kc4 = (t & 63) * 4;
    #pragma unroll
    for (int i = 0; i < 16; ++i) {
      const int r = (t >> 6) + i * 4;
      float4_ v = *(const float4_*)(x + (size_t)(m0 + r) * D_L + kc4);
      ushort4_ o;
      o[0] = f2bf(v[0]); o[1] = f2bf(v[1]); o[2] = f2bf(v[2]); o[3] = f2bf(v[3]);
      *(ushort4_*)&as_[r * 264 + kc4] = o;
    }
  }

  const float bias = be[c0 + dg * 32 + col];
  float16_ acc;
  #pragma unroll
  for (int e = 0; e < 16; ++e) acc[e] = bias;

  __syncthreads();  // the only barrier

  const unsigned short* arow = &as_[(rg * 32 + col) * 264 + q * 8];
  const unsigned short* bbase = WeT2 + (size_t)cblk * 16384 + dg * 2048 + l * 8;
  #pragma unroll
  for (int kc = 0; kc < 4; ++kc) {
    #pragma unroll
    for (int st = 0; st < 4; ++st) {
      short8 a = *(const short8*)(arow + kc * 64 + st * 16);
      short8 b = *(const short8*)(bbase + (size_t)kc * 4096 + st * 512);
      acc = __builtin_amdgcn_mfma_f32_32x32x16_bf16(a, b, acc, 0, 0, 0);
    }
  }
  #pragma unroll
  for (int e = 0; e < 16; ++e) {
    const int row = (e & 3) + 8 * (e >> 2) + 4 * q;
    pe[(size_t)(m0 + rg * 32 + row) * ENC_COLS + c0 + dg * 32 + col] = acc[e];
  }
}

// ---------------------------------------------------------------------------
// Encoder post: sample + h (bf16, decoder-A-fragment global order) + Σ(Lq-Le).
// One wave per batch row. grid 512 x 256.
// h layout: [nblk 256][rg 2][st 4][q 2][col 32][j 8]
// ---------------------------------------------------------------------------
__global__ __launch_bounds__(256) void k_enc_post(
    const float* __restrict__ pe, const float* __restrict__ ue,
    const float* __restrict__ rr, unsigned short* __restrict__ h,
    float* __restrict__ accf)
{
  const int lane = threadIdx.x & 63;
  const int w = threadIdx.x >> 6;
  const int b = blockIdx.x * 4 + w;
  const float* row = pe + (size_t)b * ENC_COLS + lane;

  float m[8], p[8], a[8];
  #pragma unroll
  for (int k = 0; k < K_C; ++k) {
    m[k] = row[k * 64]; p[k] = row[512 + k * 64]; a[k] = row[1024 + k * 64];
  }
  float amax = a[0];
  #pragma unroll
  for (int k = 1; k < K_C; ++k) amax = fmaxf(amax, a[k]);
  float sa = 0.f;
  #pragma unroll
  for (int k = 0; k < K_C; ++k) sa += __expf(a[k] - amax);
  const float lse_a = amax + __logf(sa);

  float cum[8];
  {
    float cs = 0.f;
    #pragma unroll
    for (int k = 0; k < K_C; ++k) { cs += __expf(a[k] - lse_a); cum[k] = cs; }
  }
  float ep[8];
  #pragma unroll
  for (int k = 0; k < K_C; ++k) ep[k] = __expf(p[k]);

  const int st = lane >> 4, qq = (lane >> 3) & 1, jj = lane & 7;

  float tot = 0.f;
  for (int j = 0; j < 8; ++j) {
    const int n = b + BATCH * j;
    const float rv = rr[(size_t)n * L_L + lane];
    const float uv = ue[(size_t)n * L_L + lane];
    int idx = 0;
    #pragma unroll
    for (int k = 0; k < K_C; ++k) idx += (rv > cum[k]) ? 1 : 0;
    idx = min(idx, K_C - 1);
    float msel = m[0], psel = p[0];
    #pragma unroll
    for (int k = 1; k < K_C; ++k) {
      const bool sel = (idx == k);
      msel = sel ? m[k] : msel;
      psel = sel ? p[k] : psel;
    }
    const float hv = fmaf(__expf(-0.5f * psel), uv, msel);

    const int nblk = n >> 6, rgn = (n >> 5) & 1, coln = n & 31;
    h[((((size_t)(nblk * 2 + rgn) * 4 + st) * 2 + qq) * 32 + coln) * 8 + jj] = f2bf(hv);

    float stt = 0.f;
    #pragma unroll
    for (int k = 0; k < K_C; ++k) {
      const float dd = hv - m[k];
      const float tt = a[k] + 0.5f * p[k] - 0.5f * ep[k] * dd * dd;
      stt += __expf(tt);
    }
    tot += -0.5f * hv * hv - (__logf(stt + 1e-30f) - lse_a);
  }
  #pragma unroll
  for (int off = 1; off < 64; off <<= 1) tot += __shfl_xor(tot, off, 64);
  __shared__ float red2[4];
  if (lane == 0) red2[w] = tot;
  __syncthreads();
  if (threadIdx.x == 0) atomicAdd(accf, red2[0] + red2[1] + red2[2] + red2[3]);
}

// ---------------------------------------------------------------------------
// Decoder: barrier-free fused MFMA GEMM + mixture epilogue, register-level
// software pipeline: comp k+1's 12 B-fragments load into the alternate
// register buffer while comp k's MFMAs + transcendental epilogue execute.
// Block = 64 rows x 64 d, 4 waves. grid (4, 256) x 256.
// ---------------------------------------------------------------------------
__global__ __launch_bounds__(256, 3) void k_dec(
    const unsigned short* __restrict__ hF, const float* __restrict__ x,
    const unsigned short* __restrict__ WdT2, const float* __restrict__ bd,
    float* __restrict__ accf, unsigned* __restrict__ counter,
    float* __restrict__ out)
{
  const int t = threadIdx.x;
  const int w = t >> 6, l = t & 63;
  const int col = l & 31, q = l >> 5;
  const int rg = w >> 1, dg = w & 1;
  const int dt = blockIdx.x, d0 = dt * 64;
  const int nblk = blockIdx.y, n0 = nblk * 64;
  const int colD = d0 + dg * 32 + col;

  // A fragments: 4 coalesced 16B loads
  const unsigned short* hbase = hF + ((size_t)(nblk * 2 + rg) * 4) * 512 + l * 8;
  short8 af[4];
  #pragma unroll
  for (int st = 0; st < 4; ++st) af[st] = *(const short8*)(hbase + st * 512);

  // all 24 bias values preloaded (coalesced, L2)
  float bmv[8], bpv[8], bav[8];
  #pragma unroll
  for (int c = 0; c < K_C; ++c) {
    bmv[c] = bd[c * 256 + colD];
    bpv[c] = bd[2048 + c * 256 + colD] * L2E;
    bav[c] = bd[4096 + c * 256 + colD] * L2E;
  }

  // x values for this lane's 16 C-elements
  float xv[16];
  #pragma unroll
  for (int e = 0; e < 16; ++e) {
    const int rw = (e & 3) + 8 * (e >> 2) + 4 * q;
    const int n = n0 + rg * 32 + rw;
    xv[e] = x[(size_t)(n & (BATCH - 1)) * D_L + colD];
  }

  float s_a[16], s_t[16];
  #pragma unroll
  for (int e = 0; e < 16; ++e) { s_a[e] = 0.f; s_t[e] = 0.f; }

  const unsigned short* wbase = WdT2 + dg * 2048 + l * 8;

  // register double-buffer for B fragments
  short8 bufA[3][4], bufB[3][4];
  #pragma unroll
  for (int p = 0; p < 3; ++p) {
    const unsigned short* pb = wbase + ((size_t)(0 * 3 + p) * 4 + dt) * 4096;
    #pragma unroll
    for (int st = 0; st < 4; ++st) bufA[p][st] = *(const short8*)(pb + st * 512);
  }

  #pragma unroll
  for (int comp = 0; comp < K_C; ++comp) {
    short8 (*cur)[4] = (comp & 1) ? bufB : bufA;
    short8 (*nxt)[4] = (comp & 1) ? bufA : bufB;

    if (comp < K_C - 1) {  // issue next comp's loads before using cur
      #pragma unroll
      for (int p = 0; p < 3; ++p) {
        const unsigned short* pb = wbase + ((size_t)((comp + 1) * 3 + p) * 4 + dt) * 4096;
        #pragma unroll
        for (int st = 0; st < 4; ++st) nxt[p][st] = *(const short8*)(pb + st * 512);
      }
    }

    float16_ am = {}, ap = {}, aa = {};
    #pragma unroll
    for (int st = 0; st < 4; ++st) {
      am = __builtin_amdgcn_mfma_f32_32x32x16_bf16(af[st], cur[0][st], am, 0, 0, 0);
      ap = __builtin_amdgcn_mfma_f32_32x32x16_bf16(af[st], cur[1][st], ap, 0, 0, 0);
      aa = __builtin_amdgcn_mfma_f32_32x32x16_bf16(af[st], cur[2][st], aa, 0, 0, 0);
    }

    const float bm = bmv[comp], bpL = bpv[comp], baL = bav[comp];
    #pragma unroll
    for (int e = 0; e < 16; ++e) {
      const float dd  = xv[e] - (am[e] + bm);
      const float lpL = ap[e] + bpL;
      const float laL = aa[e] + baL;
      const float ex2 = EXP2F(lpL);                        // = e^{logp}
      const float t1  = fmaf(0.5f, lpL, laL);
      const float ttL = fmaf(-C_HL2E * ex2, dd * dd, t1);
      s_a[e] += EXP2F(laL);
      s_t[e] += EXP2F(ttL);
    }
  }

  float v = 0.f;
  #pragma unroll
  for (int e = 0; e < 16; ++e)
    v += LOG2F(s_t[e] + 1e-30f) - LOG2F(s_a[e]);
  v *= LN2;
  #pragma unroll
  for (int off = 1; off < 64; off <<= 1) v += __shfl_xor(v, off, 64);
  __shared__ float red[4];
  if (l == 0) red[w] = v;
  __syncthreads();
  if (t == 0) {
    atomicAdd(accf, red[0] + red[1] + red[2] + red[3]);
    __threadfence();
    const unsigned c = atomicAdd(counter, 1u);
    if (c == 1023u) {   // last of 4*256 blocks finalizes
      __threadfence();
      const float tot = __hip_atomic_load(accf, __ATOMIC_ACQUIRE,
                                          __HIP_MEMORY_SCOPE_AGENT);
      out[0] = -(tot / (float)NTOT) + 128.0f * LOG2PI;
    }
  }
}

// ---------------------------------------------------------------------------
extern "C" void kernel_launch(void* const* d_in, const int* in_sizes, int n_in,
                              void* d_out, int out_size, void* d_ws, size_t ws_size,
                              hipStream_t stream)
{
  const float* x  = (const float*)d_in[0];
  const float* We = (const float*)d_in[1];
  const float* be = (const float*)d_in[2];
  const float* Wd = (const float*)d_in[3];
  const float* bd = (const float*)d_in[4];
  const float* ue = (const float*)d_in[5];
  const float* rr = (const float*)d_in[6];
  float* out = (float*)d_out;

  float* ws = (float*)d_ws;
  float* pe            = ws + OFF_PE;
  unsigned short* h    = (unsigned short*)(ws + OFF_H);
  unsigned short* WeT2 = (unsigned short*)(ws + OFF_WET2);
  unsigned short* WdT2 = (unsigned short*)(ws + OFF_WDT2);
  float* accf          = ws + OFF_ACC;
  unsigned* counter    = (unsigned*)(ws + OFF_CNT);

  k_prep<<<dim3(193), 256, 0, stream>>>(We, Wd, WeT2, WdT2, accf, counter);
  k_enc<<<dim3(ENC_COLS / 64, BATCH / 64), 256, 0, stream>>>(x, WeT2, be, pe);
  k_enc_post<<<dim3(BATCH / 4), 256, 0, stream>>>(pe, ue, rr, h, accf);
  k_dec<<<dim3(4, NTOT / 64), 256, 0, stream>>>(h, x, WdT2, bd, accf, counter, out);
}

// Round 9
// 134.233 us; speedup vs baseline: 1.6617x; 1.6617x over previous
//
#include <hip/hip_runtime.h>
#include <hip/hip_bf16.h>
#include <math.h>

#define D_L   256
#define L_L   64
#define K_C   8
#define BATCH 2048
#define NTOT  16384
#define ENC_COLS 1536
#define LOG2PI 1.8378770664093453f
#define L2E    1.4426950408889634f
#define LN2    0.6931471805599453f
#define C_HL2E 0.7213475204444817f   // 0.5 * log2(e)

typedef __attribute__((ext_vector_type(8)))  short short8;
typedef __attribute__((ext_vector_type(8)))  unsigned short ushort8;
typedef __attribute__((ext_vector_type(4)))  unsigned short ushort4_;
typedef __attribute__((ext_vector_type(4)))  float float4_;
typedef __attribute__((ext_vector_type(16))) float float16_;

#if defined(__has_builtin)
#  if __has_builtin(__builtin_amdgcn_exp2f)
#    define EXP2F(x) __builtin_amdgcn_exp2f(x)
#  endif
#  if __has_builtin(__builtin_amdgcn_logf)
#    define LOG2F(x) __builtin_amdgcn_logf(x)
#  endif
#endif
#ifndef EXP2F
#  define EXP2F(x) __expf((x) * LN2)
#endif
#ifndef LOG2F
#  define LOG2F(x) (__logf(x) * L2E)
#endif

// workspace layout (float offsets), total ~16.25 MB
#define OFF_PE    0                                 // 2048*1536 f32
#define OFF_H     (BATCH * ENC_COLS)                // 16384*64 bf16, 32x32 A-frag order
#define OFF_WET2  (OFF_H + NTOT * L_L / 2)          // 1536*256 bf16, 32x32 B-frag order
#define OFF_WDT2  (OFF_WET2 + ENC_COLS * D_L / 2)   // 6144*64 bf16, 32x32 B-frag order
#define OFF_ACC   (OFF_WDT2 + 6144 * 64 / 2)        // 1 f32 accumulator
#define OFF_CNT   (OFF_ACC + 1)                     // 1 u32 block counter

__device__ __forceinline__ unsigned short f2bf(float f) {
  unsigned u = __float_as_uint(f);
  return (unsigned short)((u + 0x7fffu + ((u >> 16) & 1u)) >> 16);
}

// ---------------------------------------------------------------------------
// prep: 192 uniform 64x64 tile blocks converting W's into MFMA-B-fragment
// order bf16, + 1 block zeroing accumulator+counter. Fragment order per 64x64
// (k x col) tile: [dg 2][st 4][q 2][col 32][j 8],
//   element = W[k = st*16+q*8+j][dg*32+col]
// ---------------------------------------------------------------------------
__global__ __launch_bounds__(256) void k_prep(
    const float* __restrict__ We, const float* __restrict__ Wd,
    unsigned short* __restrict__ WeT2, unsigned short* __restrict__ WdT2,
    float* __restrict__ accf, unsigned* __restrict__ counter)
{
  const int bid = blockIdx.x, t = threadIdx.x;
  if (bid == 192) {
    if (t == 0) { accf[0] = 0.0f; counter[0] = 0u; }
    return;
  }

  const float* src; int C, rowbase, colbase; float scale;
  unsigned short* dst;
  if (bid < 96) {
    const int comp = bid / 12, p = (bid % 12) >> 2, dt = bid & 3;
    src = Wd; C = 6144; rowbase = 0;
    colbase = p * 2048 + comp * 256 + dt * 64;
    scale = p ? L2E : 1.0f;
    dst = WdT2 + (size_t)bid * 4096;            // tile idx == (comp*3+p)*4+dt == bid
  } else {
    const int idx = bid - 96;
    src = We; C = ENC_COLS; rowbase = (idx & 3) * 64;
    colbase = (idx >> 2) * 64;
    scale = 1.0f;
    dst = WeT2 + (size_t)idx * 4096;            // tile idx == cblk*4+kc
  }

  __shared__ float tile[64][65];
  {
    const int col = t & 63, w0 = t >> 6;
    #pragma unroll
    for (int i = 0; i < 16; ++i) {
      const int r = w0 + i * 4;
      tile[r][col] = src[(size_t)(rowbase + r) * C + colbase + col] * scale;
    }
  }
  __syncthreads();
  const int st = t >> 6, q = (t >> 5) & 1, c = t & 31;
  #pragma unroll
  for (int dg = 0; dg < 2; ++dg) {
    ushort8 o;
    #pragma unroll
    for (int j = 0; j < 8; ++j) o[j] = f2bf(tile[st * 16 + q * 8 + j][dg * 32 + c]);
    *(ushort8*)(dst + ((((size_t)dg * 4 + st) * 2 + q) * 32 + c) * 8) = o;
  }
}

// ---------------------------------------------------------------------------
// Encoder GEMM: pe = x @ We + be. 64x64 tile, full K=256 staged in LDS once
// (single barrier), B-fragments streamed from L2. grid (24, 32) x 256.
// ---------------------------------------------------------------------------
__global__ __launch_bounds__(256) void k_enc(
    const float* __restrict__ x, const unsigned short* __restrict__ WeT2,
    const float* __restrict__ be, float* __restrict__ pe)
{
  __shared__ __align__(16) unsigned short as_[64 * 264];
  const int t = threadIdx.x;
  const int w = t >> 6, l = t & 63;
  const int col = l & 31, q = l >> 5;
  const int rg = w >> 1, dg = w & 1;
  const int m0 = blockIdx.y * 64, cblk = blockIdx.x, c0 = cblk * 64;

  {
    const int kc4 = (t & 63) * 4;
    #pragma unroll
    for (int i = 0; i < 16; ++i) {
      const int r = (t >> 6) + i * 4;
      float4_ v = *(const float4_*)(x + (size_t)(m0 + r) * D_L + kc4);
      ushort4_ o;
      o[0] = f2bf(v[0]); o[1] = f2bf(v[1]); o[2] = f2bf(v[2]); o[3] = f2bf(v[3]);
      *(ushort4_*)&as_[r * 264 + kc4] = o;
    }
  }

  const float bias = be[c0 + dg * 32 + col];
  float16_ acc;
  #pragma unroll
  for (int e = 0; e < 16; ++e) acc[e] = bias;

  __syncthreads();  // the only barrier

  const unsigned short* arow = &as_[(rg * 32 + col) * 264 + q * 8];
  const unsigned short* bbase = WeT2 + (size_t)cblk * 16384 + dg * 2048 + l * 8;
  #pragma unroll
  for (int kc = 0; kc < 4; ++kc) {
    #pragma unroll
    for (int st = 0; st < 4; ++st) {
      short8 a = *(const short8*)(arow + kc * 64 + st * 16);
      short8 b = *(const short8*)(bbase + (size_t)kc * 4096 + st * 512);
      acc = __builtin_amdgcn_mfma_f32_32x32x16_bf16(a, b, acc, 0, 0, 0);
    }
  }
  #pragma unroll
  for (int e = 0; e < 16; ++e) {
    const int row = (e & 3) + 8 * (e >> 2) + 4 * q;
    pe[(size_t)(m0 + rg * 32 + row) * ENC_COLS + c0 + dg * 32 + col] = acc[e];
  }
}

// ---------------------------------------------------------------------------
// Encoder post: sample + h (bf16, decoder-A-fragment global order) + Σ(Lq-Le).
// One wave per batch row. grid 512 x 256.
// h layout: [nblk 256][rg 2][st 4][q 2][col 32][j 8]
// ---------------------------------------------------------------------------
__global__ __launch_bounds__(256) void k_enc_post(
    const float* __restrict__ pe, const float* __restrict__ ue,
    const float* __restrict__ rr, unsigned short* __restrict__ h,
    float* __restrict__ accf)
{
  const int lane = threadIdx.x & 63;
  const int w = threadIdx.x >> 6;
  const int b = blockIdx.x * 4 + w;
  const float* row = pe + (size_t)b * ENC_COLS + lane;

  float m[8], p[8], a[8];
  #pragma unroll
  for (int k = 0; k < K_C; ++k) {
    m[k] = row[k * 64]; p[k] = row[512 + k * 64]; a[k] = row[1024 + k * 64];
  }
  float amax = a[0];
  #pragma unroll
  for (int k = 1; k < K_C; ++k) amax = fmaxf(amax, a[k]);
  float sa = 0.f;
  #pragma unroll
  for (int k = 0; k < K_C; ++k) sa += __expf(a[k] - amax);
  const float lse_a = amax + __logf(sa);

  float cum[8];
  {
    float cs = 0.f;
    #pragma unroll
    for (int k = 0; k < K_C; ++k) { cs += __expf(a[k] - lse_a); cum[k] = cs; }
  }
  float ep[8];
  #pragma unroll
  for (int k = 0; k < K_C; ++k) ep[k] = __expf(p[k]);

  const int st = lane >> 4, qq = (lane >> 3) & 1, jj = lane & 7;

  float tot = 0.f;
  for (int j = 0; j < 8; ++j) {
    const int n = b + BATCH * j;
    const float rv = rr[(size_t)n * L_L + lane];
    const float uv = ue[(size_t)n * L_L + lane];
    int idx = 0;
    #pragma unroll
    for (int k = 0; k < K_C; ++k) idx += (rv > cum[k]) ? 1 : 0;
    idx = min(idx, K_C - 1);
    float msel = m[0], psel = p[0];
    #pragma unroll
    for (int k = 1; k < K_C; ++k) {
      const bool sel = (idx == k);
      msel = sel ? m[k] : msel;
      psel = sel ? p[k] : psel;
    }
    const float hv = fmaf(__expf(-0.5f * psel), uv, msel);

    const int nblk = n >> 6, rgn = (n >> 5) & 1, coln = n & 31;
    h[((((size_t)(nblk * 2 + rgn) * 4 + st) * 2 + qq) * 32 + coln) * 8 + jj] = f2bf(hv);

    float stt = 0.f;
    #pragma unroll
    for (int k = 0; k < K_C; ++k) {
      const float dd = hv - m[k];
      const float tt = a[k] + 0.5f * p[k] - 0.5f * ep[k] * dd * dd;
      stt += __expf(tt);
    }
    tot += -0.5f * hv * hv - (__logf(stt + 1e-30f) - lse_a);
  }
  #pragma unroll
  for (int off = 1; off < 64; off <<= 1) tot += __shfl_xor(tot, off, 64);
  __shared__ float red2[4];
  if (lane == 0) red2[w] = tot;
  __syncthreads();
  if (threadIdx.x == 0) atomicAdd(accf, red2[0] + red2[1] + red2[2] + red2[3]);
}

// ---------------------------------------------------------------------------
// Decoder: barrier-free fused MFMA GEMM + mixture epilogue with a REGISTER
// double-buffer pipeline. Two NAMED buffers bA/bB alternated textually via
// macros — all indices compile-time constants so SROA keeps them in VGPRs
// (r8 post-mortem: runtime pointer select -> scratch spill -> 112MB fetch).
// Block = 64 rows x 64 d, 4 waves. grid (4, 256) x 256.
// ---------------------------------------------------------------------------
__global__ __launch_bounds__(256, 2) void k_dec(
    const unsigned short* __restrict__ hF, const float* __restrict__ x,
    const unsigned short* __restrict__ WdT2, const float* __restrict__ bd,
    float* __restrict__ accf, unsigned* __restrict__ counter,
    float* __restrict__ out)
{
  const int t = threadIdx.x;
  const int w = t >> 6, l = t & 63;
  const int col = l & 31, q = l >> 5;
  const int rg = w >> 1, dg = w & 1;
  const int dt = blockIdx.x, d0 = dt * 64;
  const int nblk = blockIdx.y, n0 = nblk * 64;
  const int colD = d0 + dg * 32 + col;

  // A fragments: 4 coalesced 16B loads
  const unsigned short* hbase = hF + ((size_t)(nblk * 2 + rg) * 4) * 512 + l * 8;
  short8 af[4];
  #pragma unroll
  for (int st = 0; st < 4; ++st) af[st] = *(const short8*)(hbase + st * 512);

  // all 24 bias values preloaded (coalesced; constant-indexed arrays)
  float bmv[8], bpv[8], bav[8];
  #pragma unroll
  for (int c = 0; c < K_C; ++c) {
    bmv[c] = bd[c * 256 + colD];
    bpv[c] = bd[2048 + c * 256 + colD] * L2E;
    bav[c] = bd[4096 + c * 256 + colD] * L2E;
  }

  // x values for this lane's 16 C-elements
  float xv[16];
  #pragma unroll
  for (int e = 0; e < 16; ++e) {
    const int rw = (e & 3) + 8 * (e >> 2) + 4 * q;
    const int n = n0 + rg * 32 + rw;
    xv[e] = x[(size_t)(n & (BATCH - 1)) * D_L + colD];
  }

  float s_a[16], s_t[16];
  #pragma unroll
  for (int e = 0; e < 16; ++e) { s_a[e] = 0.f; s_t[e] = 0.f; }

  const unsigned short* wbase = WdT2 + dg * 2048 + l * 8;

  short8 bA[3][4], bB[3][4];

#define LOADB(BUF, comp)                                                     \
  {                                                                          \
    _Pragma("unroll")                                                        \
    for (int p = 0; p < 3; ++p) {                                            \
      const unsigned short* pb =                                             \
          wbase + ((size_t)((comp) * 3 + p) * 4 + dt) * 4096;                \
      _Pragma("unroll")                                                      \
      for (int st = 0; st < 4; ++st)                                         \
        BUF[p][st] = *(const short8*)(pb + st * 512);                        \
    }                                                                        \
  }

#define COMPB(BUF, comp)                                                     \
  {                                                                          \
    float16_ am = {}, ap = {}, aa = {};                                      \
    _Pragma("unroll")                                                        \
    for (int st = 0; st < 4; ++st) {                                         \
      am = __builtin_amdgcn_mfma_f32_32x32x16_bf16(af[st], BUF[0][st], am, 0, 0, 0); \
      ap = __builtin_amdgcn_mfma_f32_32x32x16_bf16(af[st], BUF[1][st], ap, 0, 0, 0); \
      aa = __builtin_amdgcn_mfma_f32_32x32x16_bf16(af[st], BUF[2][st], aa, 0, 0, 0); \
    }                                                                        \
    const float bm = bmv[(comp)], bpL = bpv[(comp)], baL = bav[(comp)];      \
    _Pragma("unroll")                                                        \
    for (int e = 0; e < 16; ++e) {                                           \
      const float dd  = xv[e] - (am[e] + bm);                                \
      const float lpL = ap[e] + bpL;                                         \
      const float laL = aa[e] + baL;                                         \
      const float ex2 = EXP2F(lpL);                                          \
      const float t1  = fmaf(0.5f, lpL, laL);                                \
      const float ttL = fmaf(-C_HL2E * ex2, dd * dd, t1);                    \
      s_a[e] += EXP2F(laL);                                                  \
      s_t[e] += EXP2F(ttL);                                                  \
    }                                                                        \
  }

  LOADB(bA, 0)
  LOADB(bB, 1)  COMPB(bA, 0)
  LOADB(bA, 2)  COMPB(bB, 1)
  LOADB(bB, 3)  COMPB(bA, 2)
  LOADB(bA, 4)  COMPB(bB, 3)
  LOADB(bB, 5)  COMPB(bA, 4)
  LOADB(bA, 6)  COMPB(bB, 5)
  LOADB(bB, 7)  COMPB(bA, 6)
                COMPB(bB, 7)

#undef LOADB
#undef COMPB

  float v = 0.f;
  #pragma unroll
  for (int e = 0; e < 16; ++e)
    v += LOG2F(s_t[e] + 1e-30f) - LOG2F(s_a[e]);
  v *= LN2;
  #pragma unroll
  for (int off = 1; off < 64; off <<= 1) v += __shfl_xor(v, off, 64);
  __shared__ float red[4];
  if (l == 0) red[w] = v;
  __syncthreads();
  if (t == 0) {
    atomicAdd(accf, red[0] + red[1] + red[2] + red[3]);
    __threadfence();
    const unsigned c = atomicAdd(counter, 1u);
    if (c == 1023u) {   // last of 4*256 blocks finalizes
      __threadfence();
      const float tot = __hip_atomic_load(accf, __ATOMIC_ACQUIRE,
                                          __HIP_MEMORY_SCOPE_AGENT);
      out[0] = -(tot / (float)NTOT) + 128.0f * LOG2PI;
    }
  }
}

// ---------------------------------------------------------------------------
extern "C" void kernel_launch(void* const* d_in, const int* in_sizes, int n_in,
                              void* d_out, int out_size, void* d_ws, size_t ws_size,
                              hipStream_t stream)
{
  const float* x  = (const float*)d_in[0];
  const float* We = (const float*)d_in[1];
  const float* be = (const float*)d_in[2];
  const float* Wd = (const float*)d_in[3];
  const float* bd = (const float*)d_in[4];
  const float* ue = (const float*)d_in[5];
  const float* rr = (const float*)d_in[6];
  float* out = (float*)d_out;

  float* ws = (float*)d_ws;
  float* pe            = ws + OFF_PE;
  unsigned short* h    = (unsigned short*)(ws + OFF_H);
  unsigned short* WeT2 = (unsigned short*)(ws + OFF_WET2);
  unsigned short* WdT2 = (unsigned short*)(ws + OFF_WDT2);
  float* accf          = ws + OFF_ACC;
  unsigned* counter    = (unsigned*)(ws + OFF_CNT);

  k_prep<<<dim3(193), 256, 0, stream>>>(We, Wd, WeT2, WdT2, accf, counter);
  k_enc<<<dim3(ENC_COLS / 64, BATCH / 64), 256, 0, stream>>>(x, WeT2, be, pe);
  k_enc_post<<<dim3(BATCH / 4), 256, 0, stream>>>(pe, ue, rr, h, accf);
  k_dec<<<dim3(4, NTOT / 64), 256, 0, stream>>>(h, x, WdT2, bd, accf, counter, out);
}